// Round 10
// baseline (112.031 us; speedup 1.0000x reference)
//
#include <hip/hip_runtime.h>

// ---------- types & helpers ----------
typedef __attribute__((ext_vector_type(8))) short bf16x8;
typedef __attribute__((ext_vector_type(4))) float f32x4;
typedef __attribute__((ext_vector_type(4))) unsigned u32x4;

__device__ inline unsigned short f2bf(float f) {
  unsigned u = __builtin_bit_cast(unsigned, f);
  unsigned r = u + 0x7FFFu + ((u >> 16) & 1u);
  return (unsigned short)(r >> 16);
}
__device__ inline float bf2f(unsigned short s) {
  unsigned u = ((unsigned)s) << 16;
  return __builtin_bit_cast(float, u);
}
__device__ inline float fexp2(float x) { return __builtin_amdgcn_exp2f(x); }

__device__ inline void gload_lds16(const unsigned short* g, unsigned short* l) {
  __builtin_amdgcn_global_load_lds(
      (const __attribute__((address_space(1))) unsigned int*)g,
      (__attribute__((address_space(3))) unsigned int*)l, 16, 0, 0);
}

// PV key-permutation: key kappa (within 64-tile) -> slot k'
// kappa = n*16 + lg*4 + i  ->  k' = (n>>1)*32 + lg*8 + (n&1)*4 + i
__device__ __host__ inline int pv_perm(int k) {
  return ((k >> 5) & 1) * 32 + ((k >> 2) & 3) * 8 + ((k >> 4) & 1) * 4 + (k & 3);
}

// ---------- fused preprocessing: x->bf16, 4 weight transposes, mask bias + tileok ----------
__global__ __launch_bounds__(256) void prep_kernel(
    const float* __restrict__ x, const int* __restrict__ mask,
    const float* __restrict__ w_q, const float* __restrict__ w_d,
    const float* __restrict__ w_k, const float* __restrict__ w_v,
    unsigned short* __restrict__ x_bf, unsigned short* __restrict__ wqdt,
    unsigned short* __restrict__ wkvt, float* __restrict__ bias,
    int* __restrict__ tileok) {
  int bid = blockIdx.x;
  if (bid < 1024) {  // x fp32 -> bf16, 4096 elems/block
    int base = bid * 4096 + threadIdx.x * 4;
#pragma unroll
    for (int it = 0; it < 4; ++it) {
      int idx = base + it * 1024;
      float4 v = *(const float4*)&x[idx];
      ushort4 o;
      o.x = f2bf(v.x); o.y = f2bf(v.y); o.z = f2bf(v.z); o.w = f2bf(v.w);
      *(ushort4*)&x_bf[idx] = o;
    }
    return;
  }
  int tb = bid - 1024;
  if (tb >= 1408) {  // mask -> additive bias + per-64-key-tile all-valid flag
    int i = (tb - 1408) * 256 + threadIdx.x;
    int mv = mask[i];
    bias[i] = mv ? 0.0f : -1e30f;
    int ok = __all(mv != 0);  // each wave covers exactly one aligned 64-key tile
    if ((threadIdx.x & 63) == 0) tileok[i >> 6] = ok;
    return;
  }
  const float* in; unsigned short* out; int R, C, tr, tc;
  if (tb < 1024)      { in = w_q; out = wqdt;               R = 1024; C = 1024; tr = tb >> 5; tc = tb & 31; }
  else if (tb < 1152) { int t2 = tb - 1024; in = w_d; out = wqdt + 1024 * 1024; R = 1024; C = 128; tr = t2 >> 2; tc = t2 & 3; }
  else if (tb < 1280) { int t2 = tb - 1152; in = w_k; out = wkvt;               R = 128; C = 1024; tr = t2 >> 5; tc = t2 & 31; }
  else                { int t2 = tb - 1280; in = w_v; out = wkvt + 1024 * 128;  R = 128; C = 1024; tr = t2 >> 5; tc = t2 & 31; }
  __shared__ float t[32][33];
  int r0 = tr * 32, c0 = tc * 32;
  int tx = threadIdx.x & 31, ty = threadIdx.x >> 5;
  for (int r = ty; r < 32; r += 8)
    t[r][tx] = in[(size_t)(r0 + r) * C + c0 + tx];
  __syncthreads();
  for (int cc = ty; cc < 32; cc += 8)
    out[(size_t)(c0 + cc) * R + r0 + tx] = f2bf(t[tx][cc]);
}

// ---------- GEMM: C[M][N] = A[M][K] * Bt[N][K]^T, bf16 in/out, fp32 accum ----------
// M-tile 128, N-tile BN (128 or 64). 4 waves.
template <int BN>
__global__ __launch_bounds__(256) void gemm_bt(const unsigned short* __restrict__ A, int lda,
                                               const unsigned short* __restrict__ Bt, int ldb,
                                               unsigned short* __restrict__ C, int ldc,
                                               int K) {
  constexpr int WM = (BN == 128) ? 2 : 4;  // waves along M
  constexpr int WN = 4 / WM;               // waves along N
  constexpr int MR = 128 / WM / 16;        // m-frags per wave
  constexpr int NR = BN / WN / 16;         // n-frags per wave
  constexpr int RPW = 128 / WM;            // rows per wave (M)
  constexpr int CPW = BN / WN;             // cols per wave (N)
  __shared__ unsigned short As[128 * 32];
  __shared__ unsigned short Bs[BN * 32];
  int m0 = blockIdx.x * 128, n0 = blockIdx.y * BN;
  int tid = threadIdx.x, w = tid >> 6, l = tid & 63;
  int lr = l & 15, lg = l >> 4;
  int wr = w / WN, wc = w % WN;
  f32x4 acc[MR][NR] = {};

  for (int k0 = 0; k0 < K; k0 += 32) {
    __syncthreads();
#pragma unroll
    for (int it = 0; it < 2; ++it) {
      int c = w * 2 + it;
      int row = c * 16 + (l >> 2);
      int col = (l & 3) * 8;
      gload_lds16(&A[(size_t)(m0 + row) * lda + k0 + col], &As[c * 512 + l * 8]);
    }
    if constexpr (BN == 128) {
#pragma unroll
      for (int it = 0; it < 2; ++it) {
        int c = w * 2 + it;
        int row = c * 16 + (l >> 2);
        int col = (l & 3) * 8;
        gload_lds16(&Bt[(size_t)(n0 + row) * ldb + k0 + col], &Bs[c * 512 + l * 8]);
      }
    } else {
      int row = w * 16 + (l >> 2);
      int col = (l & 3) * 8;
      gload_lds16(&Bt[(size_t)(n0 + row) * ldb + k0 + col], &Bs[w * 512 + l * 8]);
    }
    __syncthreads();
    bf16x8 af[MR], bfr[NR];
#pragma unroll
    for (int m = 0; m < MR; ++m)
      af[m] = *(const bf16x8*)&As[(wr * RPW + m * 16 + lr) * 32 + lg * 8];
#pragma unroll
    for (int n = 0; n < NR; ++n)
      bfr[n] = *(const bf16x8*)&Bs[(wc * CPW + n * 16 + lr) * 32 + lg * 8];
    __builtin_amdgcn_s_setprio(1);
#pragma unroll
    for (int m = 0; m < MR; ++m)
#pragma unroll
      for (int n = 0; n < NR; ++n)
        acc[m][n] = __builtin_amdgcn_mfma_f32_16x16x32_bf16(af[m], bfr[n], acc[m][n], 0, 0, 0);
    __builtin_amdgcn_s_setprio(0);
  }

#pragma unroll
  for (int m = 0; m < MR; ++m)
#pragma unroll
    for (int n = 0; n < NR; ++n)
#pragma unroll
      for (int i = 0; i < 4; ++i)
        C[(size_t)(m0 + wr * RPW + m * 16 + lg * 4 + i) * ldc + n0 + wc * CPW + n * 16 + lr] =
            f2bf(acc[m][n][i]);
}

// ---------- gemm2 with fused V transpose+permute epilogue ----------
// C = latent[4096x128] x wkvt[2048x128]^T. grid (32,16). by<8: K half -> kvK rows.
// by>=8: V half -> vt[(b*16+h)*64+d][tile64*64 + pv_perm(tok&63)] (transposed).
__global__ __launch_bounds__(256) void gemm_kv(const unsigned short* __restrict__ A,
                                               const unsigned short* __restrict__ Bt,
                                               unsigned short* __restrict__ kvK,
                                               unsigned short* __restrict__ vt) {
  __shared__ unsigned short As[128 * 32];
  __shared__ unsigned short Bs[128 * 32];
  int m0 = blockIdx.x * 128, n0 = blockIdx.y * 128;
  int tid = threadIdx.x, w = tid >> 6, l = tid & 63;
  int lr = l & 15, lg = l >> 4;
  int wr = w >> 1, wc = w & 1;
  f32x4 acc[4][4] = {};

  for (int k0 = 0; k0 < 128; k0 += 32) {
    __syncthreads();
#pragma unroll
    for (int it = 0; it < 2; ++it) {
      int c = w * 2 + it;
      int row = c * 16 + (l >> 2);
      int col = (l & 3) * 8;
      gload_lds16(&A[(size_t)(m0 + row) * 1152 + k0 + col], &As[c * 512 + l * 8]);
      gload_lds16(&Bt[(size_t)(n0 + row) * 128 + k0 + col], &Bs[c * 512 + l * 8]);
    }
    __syncthreads();
    bf16x8 af[4], bfr[4];
#pragma unroll
    for (int m = 0; m < 4; ++m)
      af[m] = *(const bf16x8*)&As[(wr * 64 + m * 16 + lr) * 32 + lg * 8];
#pragma unroll
    for (int n = 0; n < 4; ++n)
      bfr[n] = *(const bf16x8*)&Bs[(wc * 64 + n * 16 + lr) * 32 + lg * 8];
    __builtin_amdgcn_s_setprio(1);
#pragma unroll
    for (int m = 0; m < 4; ++m)
#pragma unroll
      for (int n = 0; n < 4; ++n)
        acc[m][n] = __builtin_amdgcn_mfma_f32_16x16x32_bf16(af[m], bfr[n], acc[m][n], 0, 0, 0);
    __builtin_amdgcn_s_setprio(0);
  }

  if (blockIdx.y < 8) {  // K half: plain row-major write (ldc 2048)
#pragma unroll
    for (int m = 0; m < 4; ++m)
#pragma unroll
      for (int n = 0; n < 4; ++n)
#pragma unroll
        for (int i = 0; i < 4; ++i)
          kvK[(size_t)(m0 + wr * 64 + m * 16 + lg * 4 + i) * 2048 + n0 + wc * 64 + n * 16 + lr] =
              f2bf(acc[m][n][i]);
  } else {  // V half: transposed + pv_perm'd, 4 consecutive tokens -> contiguous ushort4
#pragma unroll
    for (int m = 0; m < 4; ++m)
#pragma unroll
      for (int n = 0; n < 4; ++n) {
        int vc = n0 - 1024 + wc * 64 + n * 16 + lr;  // v-column 0..1023
        int hh = vc >> 6, dd = vc & 63;
        int row0 = m0 + wr * 64 + m * 16 + lg * 4;   // token row (aligned 4)
        int bb = row0 >> 11, t0 = row0 & 2047;
        size_t vrow = (size_t)((bb * 16 + hh) * 64 + dd);
        int slot = (t0 >> 6) * 64 + pv_perm(t0 & 63);
        ushort4 o;
        o.x = f2bf(acc[m][n][0]); o.y = f2bf(acc[m][n][1]);
        o.z = f2bf(acc[m][n][2]); o.w = f2bf(acc[m][n][3]);
        *(ushort4*)&vt[vrow * 2048 + slot] = o;
      }
  }
}

// ---------- flash attention: LDS-free, barrier-free, register-resident ----------
// grid (bh=32, y=64), qt32 = 63 - y (heaviest first). 1 wave/block (64 thr).
// Wave owns 32 q rows (2 column-blocks qb of 16). K/V MFMA fragments loaded
// straight from global (16B/lane), software-pipelined across kt.
__global__ __launch_bounds__(64, 2) void attn_kernel(const unsigned short* __restrict__ qg,
                                                     const unsigned short* __restrict__ kvg,
                                                     const unsigned short* __restrict__ vtg,
                                                     const float* __restrict__ biasg,
                                                     const int* __restrict__ tileokg,
                                                     float* __restrict__ outg) {
  const int bh = blockIdx.x, qt32 = 63 - blockIdx.y;
  const int b = bh >> 4, h = bh & 15;
  const int l = threadIdx.x & 63, lr = l & 15, lg = l >> 4;
  const int qrow0 = qt32 * 32;
  const int nkv = (qt32 >> 1) + 1;
  const int dov0 = (qt32 & 1) * 32 + lr;  // causal limit for qb=0 row; +16 for qb=1
  const float QSCALE = 0.125f * 1.44269504089f;  // 1/sqrt(dh) * log2(e)

  // Q fragments (pre-scaled), two 16-row column blocks
  bf16x8 qf[2][2];
#pragma unroll
  for (int qb = 0; qb < 2; ++qb)
#pragma unroll
    for (int ks = 0; ks < 2; ++ks) {
      bf16x8 raw = *(const bf16x8*)&qg[(size_t)(b * 2048 + qrow0 + qb * 16 + lr) * 1152 +
                                       h * 64 + ks * 32 + lg * 8];
#pragma unroll
      for (int j = 0; j < 8; ++j)
        raw[j] = (short)f2bf(bf2f((unsigned short)raw[j]) * QSCALE);
      qf[qb][ks] = raw;
    }

  // per-lane base pointers for K/V fragment loads
  const unsigned short* kptr = kvg + (size_t)(b * 2048 + lr) * 2048 + h * 64 + lg * 8;
  const unsigned short* vptr = vtg + (size_t)(bh * 64 + lr) * 2048 + lg * 8;

  // prologue: fragments of tile 0
  bf16x8 kf[4][2], vf[4][2];
#pragma unroll
  for (int n = 0; n < 4; ++n)
#pragma unroll
    for (int ks = 0; ks < 2; ++ks) {
      kf[n][ks] = *(const bf16x8*)(kptr + (size_t)(n * 16) * 2048 + ks * 32);
      vf[n][ks] = *(const bf16x8*)(vptr + (size_t)(n * 16) * 2048 + ks * 32);
    }

  f32x4 acc[4][2] = {};          // [dt][qb]
  float m_i[2] = {-1e30f, -1e30f};
  float l_part[2] = {0.f, 0.f};

  for (int kt = 0; kt < nkv; ++kt) {
    // S^T = K Q^T: lane (lr,lg), qb: q-row = qrow0+qb*16+lr, keys n*16+lg*4+i
    f32x4 s[2][4];
    __builtin_amdgcn_s_setprio(1);
#pragma unroll
    for (int qb = 0; qb < 2; ++qb)
#pragma unroll
      for (int n = 0; n < 4; ++n) {
        f32x4 z = {};
#pragma unroll
        for (int ks = 0; ks < 2; ++ks)
          z = __builtin_amdgcn_mfma_f32_16x16x32_bf16(kf[n][ks], qf[qb][ks], z, 0, 0, 0);
        s[qb][n] = z;
      }
    __builtin_amdgcn_s_setprio(0);

    // prefetch K(kt+1) — K last used above; hides under softmax+PV
    if (kt + 1 < nkv) {
#pragma unroll
      for (int n = 0; n < 4; ++n)
#pragma unroll
        for (int ks = 0; ks < 2; ++ks)
          kf[n][ks] = *(const bf16x8*)(kptr + (size_t)((kt + 1) * 64 + n * 16) * 2048 + ks * 32);
    }

    const int tok = tileokg[b * 32 + kt];
    const bool diag = (kt == nkv - 1);
    float mx[2] = {-1e30f, -1e30f};
    if (tok) {
      if (diag) {
#pragma unroll
        for (int qb = 0; qb < 2; ++qb)
#pragma unroll
          for (int n = 0; n < 4; ++n)
#pragma unroll
            for (int i = 0; i < 4; ++i) {
              int keyl = n * 16 + lg * 4 + i;
              float v = (keyl <= dov0 + qb * 16) ? s[qb][n][i] : -1e30f;
              s[qb][n][i] = v;
              mx[qb] = fmaxf(mx[qb], v);
            }
      } else {
#pragma unroll
        for (int qb = 0; qb < 2; ++qb)
#pragma unroll
          for (int n = 0; n < 4; ++n)
#pragma unroll
            for (int i = 0; i < 4; ++i)
              mx[qb] = fmaxf(mx[qb], s[qb][n][i]);
      }
    } else {  // rare general-mask path
#pragma unroll
      for (int n = 0; n < 4; ++n)
#pragma unroll
        for (int i = 0; i < 4; ++i) {
          int keyl = n * 16 + lg * 4 + i;
          float bsv = biasg[b * 2048 + kt * 64 + keyl];
#pragma unroll
          for (int qb = 0; qb < 2; ++qb) {
            float v = s[qb][n][i] + bsv;
            if (diag) v = (keyl <= dov0 + qb * 16) ? v : -1e30f;
            s[qb][n][i] = v;
            mx[qb] = fmaxf(mx[qb], v);
          }
        }
    }
#pragma unroll
    for (int qb = 0; qb < 2; ++qb) {
      mx[qb] = fmaxf(mx[qb], __shfl_xor(mx[qb], 16, 64));
      mx[qb] = fmaxf(mx[qb], __shfl_xor(mx[qb], 32, 64));
    }

    // T13 defer-rescale (THR=8 in log2 domain)
    float g = fmaxf(mx[0] - m_i[0], mx[1] - m_i[1]);
    if (__any(g > 8.0f)) {
#pragma unroll
      for (int qb = 0; qb < 2; ++qb) {
        float mn = fmaxf(m_i[qb], mx[qb]);
        float sc = fexp2(m_i[qb] - mn);
        m_i[qb] = mn;
        l_part[qb] *= sc;
        float scb[4];
#pragma unroll
        for (int i = 0; i < 4; ++i) scb[i] = __shfl(sc, lg * 4 + i, 64);
#pragma unroll
        for (int dt = 0; dt < 4; ++dt)
#pragma unroll
          for (int i = 0; i < 4; ++i) acc[dt][qb][i] *= scb[i];
      }
    }

#pragma unroll
    for (int qb = 0; qb < 2; ++qb) {
      float rs = 0.f;
#pragma unroll
      for (int n = 0; n < 4; ++n)
#pragma unroll
        for (int i = 0; i < 4; ++i) {
          float e = fexp2(s[qb][n][i] - m_i[qb]);
          s[qb][n][i] = e;
          rs += e;
        }
      l_part[qb] += rs;
    }

    // P -> PV A-fragments in registers (V pre-permuted by pv_perm)
    bf16x8 paf[2][2];
#pragma unroll
    for (int qb = 0; qb < 2; ++qb)
#pragma unroll
      for (int ks = 0; ks < 2; ++ks) {
        unsigned t0, t1, t2, t3;
        asm("v_cvt_pk_bf16_f32 %0, %1, %2" : "=v"(t0) : "v"(s[qb][2 * ks][0]), "v"(s[qb][2 * ks][1]));
        asm("v_cvt_pk_bf16_f32 %0, %1, %2" : "=v"(t1) : "v"(s[qb][2 * ks][2]), "v"(s[qb][2 * ks][3]));
        asm("v_cvt_pk_bf16_f32 %0, %1, %2" : "=v"(t2) : "v"(s[qb][2 * ks + 1][0]), "v"(s[qb][2 * ks + 1][1]));
        asm("v_cvt_pk_bf16_f32 %0, %1, %2" : "=v"(t3) : "v"(s[qb][2 * ks + 1][2]), "v"(s[qb][2 * ks + 1][3]));
        u32x4 uv;
        uv[0] = t0; uv[1] = t1; uv[2] = t2; uv[3] = t3;
        paf[qb][ks] = __builtin_bit_cast(bf16x8, uv);
      }

    // O += P V
    __builtin_amdgcn_s_setprio(1);
#pragma unroll
    for (int ks = 0; ks < 2; ++ks)
#pragma unroll
      for (int dt = 0; dt < 4; ++dt)
#pragma unroll
        for (int qb = 0; qb < 2; ++qb)
          acc[dt][qb] = __builtin_amdgcn_mfma_f32_16x16x32_bf16(paf[qb][ks], vf[dt][ks], acc[dt][qb], 0, 0, 0);
    __builtin_amdgcn_s_setprio(0);

    // prefetch V(kt+1) — V last used above; hides under next QK^T+softmax
    if (kt + 1 < nkv) {
#pragma unroll
      for (int dt = 0; dt < 4; ++dt)
#pragma unroll
        for (int ks = 0; ks < 2; ++ks)
          vf[dt][ks] = *(const bf16x8*)(vptr + (size_t)(dt * 16) * 2048 + (kt + 1) * 64 + ks * 32);
    }
  }

  // epilogue: finish l reduction, normalize, store
#pragma unroll
  for (int qb = 0; qb < 2; ++qb) {
    float lt = l_part[qb];
    lt += __shfl_xor(lt, 16, 64);
    lt += __shfl_xor(lt, 32, 64);
    float inv = 1.f / lt;
    float invb[4];
#pragma unroll
    for (int i = 0; i < 4; ++i) invb[i] = __shfl(inv, lg * 4 + i, 64);
#pragma unroll
    for (int dt = 0; dt < 4; ++dt)
#pragma unroll
      for (int i = 0; i < 4; ++i)
        outg[(size_t)(b * 2048 + qrow0 + qb * 16 + lg * 4 + i) * 1024 + h * 64 + dt * 16 + lr] =
            acc[dt][qb][i] * invb[i];
  }
}

// ---------- launch ----------
extern "C" void kernel_launch(void* const* d_in, const int* in_sizes, int n_in,
                              void* d_out, int out_size, void* d_ws, size_t ws_size,
                              hipStream_t stream) {
  const float* x    = (const float*)d_in[0];
  const int*   mask = (const int*)d_in[1];
  const float* w_q  = (const float*)d_in[2];
  const float* w_d  = (const float*)d_in[3];
  const float* w_k  = (const float*)d_in[4];
  const float* w_v  = (const float*)d_in[5];
  float* out = (float*)d_out;

  char* ws = (char*)d_ws;
  size_t off = 0;
  auto alloc = [&](size_t elems) {
    unsigned short* p = (unsigned short*)(ws + off);
    off += ((elems * 2 + 255) & ~(size_t)255);
    return p;
  };
  unsigned short* x_bf = alloc(4194304);      // [4096][1024]
  unsigned short* wqdt = alloc(1152 * 1024);  // [1152][1024]
  unsigned short* wkvt = alloc(2048 * 128);   // [2048][128]
  unsigned short* qlat = alloc(4096 * 1152);  // [4096][1152]: q | latent
  unsigned short* kv   = alloc(4096 * 2048);  // [4096][2048]: K in cols 0..1023 (V half unused)
  unsigned short* vt   = alloc(4194304);      // [32][64][2048], keys pv_perm'd per 64-tile
  float* bias = (float*)alloc(8192);          // 4096 floats
  int* tileok = (int*)alloc(128);             // 64 ints

  prep_kernel<<<2448, 256, 0, stream>>>(x, mask, w_q, w_d, w_k, w_v, x_bf, wqdt, wkvt, bias, tileok);

  gemm_bt<64><<<dim3(32, 18), 256, 0, stream>>>(x_bf, 1024, wqdt, 1024, qlat, 1152, 1024);
  gemm_kv<<<dim3(32, 16), 256, 0, stream>>>(qlat + 1024, wkvt, kv, vt);

  attn_kernel<<<dim3(32, 64), 64, 0, stream>>>(qlat, kv, vt, bias, tileok, out);
}

// Round 11
// 103.203 us; speedup vs baseline: 1.0855x; 1.0855x over previous
//
#include <hip/hip_runtime.h>

// ---------- types & helpers ----------
typedef __attribute__((ext_vector_type(8))) short bf16x8;
typedef __attribute__((ext_vector_type(4))) float f32x4;
typedef __attribute__((ext_vector_type(4))) unsigned u32x4;

__device__ inline unsigned short f2bf(float f) {
  unsigned u = __builtin_bit_cast(unsigned, f);
  unsigned r = u + 0x7FFFu + ((u >> 16) & 1u);
  return (unsigned short)(r >> 16);
}
__device__ inline float bf2f(unsigned short s) {
  unsigned u = ((unsigned)s) << 16;
  return __builtin_bit_cast(float, u);
}
__device__ inline float fexp2(float x) { return __builtin_amdgcn_exp2f(x); }

__device__ inline void gload_lds16(const unsigned short* g, unsigned short* l) {
  __builtin_amdgcn_global_load_lds(
      (const __attribute__((address_space(1))) unsigned int*)g,
      (__attribute__((address_space(3))) unsigned int*)l, 16, 0, 0);
}

// PV key-permutation: key kappa (within 64-tile) -> slot k'
__device__ __host__ inline int pv_perm(int k) {
  return ((k >> 5) & 1) * 32 + ((k >> 2) & 3) * 8 + ((k >> 4) & 1) * 4 + (k & 3);
}

// ---------- fused preprocessing: x->bf16, 4 weight transposes, mask bias + tileok ----------
__global__ __launch_bounds__(256) void prep_kernel(
    const float* __restrict__ x, const int* __restrict__ mask,
    const float* __restrict__ w_q, const float* __restrict__ w_d,
    const float* __restrict__ w_k, const float* __restrict__ w_v,
    unsigned short* __restrict__ x_bf, unsigned short* __restrict__ wqdt,
    unsigned short* __restrict__ wkvt, float* __restrict__ bias,
    int* __restrict__ tileok) {
  int bid = blockIdx.x;
  if (bid < 1024) {  // x fp32 -> bf16
    int base = bid * 4096 + threadIdx.x * 4;
#pragma unroll
    for (int it = 0; it < 4; ++it) {
      int idx = base + it * 1024;
      float4 v = *(const float4*)&x[idx];
      ushort4 o;
      o.x = f2bf(v.x); o.y = f2bf(v.y); o.z = f2bf(v.z); o.w = f2bf(v.w);
      *(ushort4*)&x_bf[idx] = o;
    }
    return;
  }
  int tb = bid - 1024;
  if (tb >= 1408) {  // mask -> additive bias + per-64-key-tile all-valid flag
    int i = (tb - 1408) * 256 + threadIdx.x;
    int mv = mask[i];
    bias[i] = mv ? 0.0f : -1e30f;
    int ok = __all(mv != 0);
    if ((threadIdx.x & 63) == 0) tileok[i >> 6] = ok;
    return;
  }
  const float* in; unsigned short* out; int R, C, tr, tc;
  if (tb < 1024)      { in = w_q; out = wqdt;               R = 1024; C = 1024; tr = tb >> 5; tc = tb & 31; }
  else if (tb < 1152) { int t2 = tb - 1024; in = w_d; out = wqdt + 1024 * 1024; R = 1024; C = 128; tr = t2 >> 2; tc = t2 & 3; }
  else if (tb < 1280) { int t2 = tb - 1152; in = w_k; out = wkvt;               R = 128; C = 1024; tr = t2 >> 5; tc = t2 & 31; }
  else                { int t2 = tb - 1280; in = w_v; out = wkvt + 1024 * 128;  R = 128; C = 1024; tr = t2 >> 5; tc = t2 & 31; }
  __shared__ float t[32][33];
  int r0 = tr * 32, c0 = tc * 32;
  int tx = threadIdx.x & 31, ty = threadIdx.x >> 5;
  for (int r = ty; r < 32; r += 8)
    t[r][tx] = in[(size_t)(r0 + r) * C + c0 + tx];
  __syncthreads();
  for (int cc = ty; cc < 32; cc += 8)
    out[(size_t)(c0 + cc) * R + r0 + tx] = f2bf(t[tx][cc]);
}

// ---------- GEMM: C[M][N] = A[M][K] * Bt[N][K]^T ----------
template <int BN>
__global__ __launch_bounds__(256) void gemm_bt(const unsigned short* __restrict__ A, int lda,
                                               const unsigned short* __restrict__ Bt, int ldb,
                                               unsigned short* __restrict__ C, int ldc,
                                               int K) {
  constexpr int WM = (BN == 128) ? 2 : 4;
  constexpr int WN = 4 / WM;
  constexpr int MR = 128 / WM / 16;
  constexpr int NR = BN / WN / 16;
  constexpr int RPW = 128 / WM;
  constexpr int CPW = BN / WN;
  __shared__ unsigned short As[128 * 32];
  __shared__ unsigned short Bs[BN * 32];
  int m0 = blockIdx.x * 128, n0 = blockIdx.y * BN;
  int tid = threadIdx.x, w = tid >> 6, l = tid & 63;
  int lr = l & 15, lg = l >> 4;
  int wr = w / WN, wc = w % WN;
  f32x4 acc[MR][NR] = {};

  for (int k0 = 0; k0 < K; k0 += 32) {
    __syncthreads();
#pragma unroll
    for (int it = 0; it < 2; ++it) {
      int c = w * 2 + it;
      int row = c * 16 + (l >> 2);
      int col = (l & 3) * 8;
      gload_lds16(&A[(size_t)(m0 + row) * lda + k0 + col], &As[c * 512 + l * 8]);
    }
    if constexpr (BN == 128) {
#pragma unroll
      for (int it = 0; it < 2; ++it) {
        int c = w * 2 + it;
        int row = c * 16 + (l >> 2);
        int col = (l & 3) * 8;
        gload_lds16(&Bt[(size_t)(n0 + row) * ldb + k0 + col], &Bs[c * 512 + l * 8]);
      }
    } else {
      int row = w * 16 + (l >> 2);
      int col = (l & 3) * 8;
      gload_lds16(&Bt[(size_t)(n0 + row) * ldb + k0 + col], &Bs[w * 512 + l * 8]);
    }
    __syncthreads();
    bf16x8 af[MR], bfr[NR];
#pragma unroll
    for (int m = 0; m < MR; ++m)
      af[m] = *(const bf16x8*)&As[(wr * RPW + m * 16 + lr) * 32 + lg * 8];
#pragma unroll
    for (int n = 0; n < NR; ++n)
      bfr[n] = *(const bf16x8*)&Bs[(wc * CPW + n * 16 + lr) * 32 + lg * 8];
    __builtin_amdgcn_s_setprio(1);
#pragma unroll
    for (int m = 0; m < MR; ++m)
#pragma unroll
      for (int n = 0; n < NR; ++n)
        acc[m][n] = __builtin_amdgcn_mfma_f32_16x16x32_bf16(af[m], bfr[n], acc[m][n], 0, 0, 0);
    __builtin_amdgcn_s_setprio(0);
  }

#pragma unroll
  for (int m = 0; m < MR; ++m)
#pragma unroll
    for (int n = 0; n < NR; ++n)
#pragma unroll
      for (int i = 0; i < 4; ++i)
        C[(size_t)(m0 + wr * RPW + m * 16 + lg * 4 + i) * ldc + n0 + wc * CPW + n * 16 + lr] =
            f2bf(acc[m][n][i]);
}

// ---------- gemm2 with fused V transpose+permute epilogue ----------
__global__ __launch_bounds__(256) void gemm_kv(const unsigned short* __restrict__ A,
                                               const unsigned short* __restrict__ Bt,
                                               unsigned short* __restrict__ kvK,
                                               unsigned short* __restrict__ vt) {
  __shared__ unsigned short As[128 * 32];
  __shared__ unsigned short Bs[128 * 32];
  int m0 = blockIdx.x * 128, n0 = blockIdx.y * 128;
  int tid = threadIdx.x, w = tid >> 6, l = tid & 63;
  int lr = l & 15, lg = l >> 4;
  int wr = w >> 1, wc = w & 1;
  f32x4 acc[4][4] = {};

  for (int k0 = 0; k0 < 128; k0 += 32) {
    __syncthreads();
#pragma unroll
    for (int it = 0; it < 2; ++it) {
      int c = w * 2 + it;
      int row = c * 16 + (l >> 2);
      int col = (l & 3) * 8;
      gload_lds16(&A[(size_t)(m0 + row) * 1152 + k0 + col], &As[c * 512 + l * 8]);
      gload_lds16(&Bt[(size_t)(n0 + row) * 128 + k0 + col], &Bs[c * 512 + l * 8]);
    }
    __syncthreads();
    bf16x8 af[4], bfr[4];
#pragma unroll
    for (int m = 0; m < 4; ++m)
      af[m] = *(const bf16x8*)&As[(wr * 64 + m * 16 + lr) * 32 + lg * 8];
#pragma unroll
    for (int n = 0; n < 4; ++n)
      bfr[n] = *(const bf16x8*)&Bs[(wc * 64 + n * 16 + lr) * 32 + lg * 8];
    __builtin_amdgcn_s_setprio(1);
#pragma unroll
    for (int m = 0; m < 4; ++m)
#pragma unroll
      for (int n = 0; n < 4; ++n)
        acc[m][n] = __builtin_amdgcn_mfma_f32_16x16x32_bf16(af[m], bfr[n], acc[m][n], 0, 0, 0);
    __builtin_amdgcn_s_setprio(0);
  }

  if (blockIdx.y < 8) {  // K half
#pragma unroll
    for (int m = 0; m < 4; ++m)
#pragma unroll
      for (int n = 0; n < 4; ++n)
#pragma unroll
        for (int i = 0; i < 4; ++i)
          kvK[(size_t)(m0 + wr * 64 + m * 16 + lg * 4 + i) * 2048 + n0 + wc * 64 + n * 16 + lr] =
              f2bf(acc[m][n][i]);
  } else {  // V half: transposed + pv_perm'd
#pragma unroll
    for (int m = 0; m < 4; ++m)
#pragma unroll
      for (int n = 0; n < 4; ++n) {
        int vc = n0 - 1024 + wc * 64 + n * 16 + lr;
        int hh = vc >> 6, dd = vc & 63;
        int row0 = m0 + wr * 64 + m * 16 + lg * 4;
        int bb = row0 >> 11, t0 = row0 & 2047;
        size_t vrow = (size_t)((bb * 16 + hh) * 64 + dd);
        int slot = (t0 >> 6) * 64 + pv_perm(t0 & 63);
        ushort4 o;
        o.x = f2bf(acc[m][n][0]); o.y = f2bf(acc[m][n][1]);
        o.z = f2bf(acc[m][n][2]); o.w = f2bf(acc[m][n][3]);
        *(ushort4*)&vt[vrow * 2048 + slot] = o;
      }
  }
}

// ---------- flash attention, split-K chunks of <=8 KV tiles ----------
// grid (bh=32, y=160). y2 = 159 - y maps to (qt32, chunk): bands of 16 q-tiles
// with 1/2/3/4 chunks. Block = 2 waves, QBLK=32; wave w owns rows qt32*32+w*16..+15.
// Writes unnormalized partial (O, m, l) to part[bh*160 + y2].
#define PSTRIDE 2112  // 32*64 O + 32 m + 32 l floats
__global__ __launch_bounds__(128, 4) void attn_kernel(const unsigned short* __restrict__ qg,
                                                      const unsigned short* __restrict__ kvg,
                                                      const unsigned short* __restrict__ vtg,
                                                      const float* __restrict__ biasg,
                                                      const int* __restrict__ tileokg,
                                                      float* __restrict__ partg) {
  const int bh = blockIdx.x;
  const int y2 = 159 - blockIdx.y;
  int qt32, c;
  if (y2 < 16)      { qt32 = y2; c = 0; }
  else if (y2 < 48) { int t = y2 - 16; qt32 = 16 + (t >> 1); c = t & 1; }
  else if (y2 < 96) { int t = y2 - 48; qt32 = 32 + t / 3; c = t - (t / 3) * 3; }
  else              { int t = y2 - 96; qt32 = 48 + (t >> 2); c = t & 3; }
  const int nkv = (qt32 >> 1) + 1;
  const int k0t = c * 8;
  const int kend = min(nkv, k0t + 8);

  const int b = bh >> 4, h = bh & 15;
  const int tid = threadIdx.x, w = tid >> 6, l = tid & 63;
  const int lr = l & 15, lg = l >> 4;

  __shared__ unsigned short Ks[64 * 72];  // [key][d]
  __shared__ unsigned short Vs[64 * 72];  // [d][permuted key]

  const int qrow0 = qt32 * 32 + w * 16;
  const int diagoff = (qt32 & 1) * 32 + w * 16 + lr;
  const float QSCALE = 0.125f * 1.44269504089f;

  bf16x8 qf[2];
#pragma unroll
  for (int s = 0; s < 2; ++s) {
    bf16x8 raw = *(const bf16x8*)&qg[(size_t)(b * 2048 + qrow0 + lr) * 1152 + h * 64 + s * 32 + lg * 8];
#pragma unroll
    for (int j = 0; j < 8; ++j)
      raw[j] = (short)f2bf(bf2f((unsigned short)raw[j]) * QSCALE);
    qf[s] = raw;
  }

  f32x4 acc[4] = {};
  float m_i = -1e30f;
  float l_part = 0.f;

  // prologue: stage tile k0t
  bf16x8 kreg[4], vreg[4];
#pragma unroll
  for (int it = 0; it < 4; ++it) {
    int slot = it * 128 + tid, row = slot >> 3, c8 = (slot & 7) * 8;
    kreg[it] = *(const bf16x8*)&kvg[(size_t)(b * 2048 + k0t * 64 + row) * 2048 + h * 64 + c8];
    vreg[it] = *(const bf16x8*)&vtg[((size_t)(bh * 64 + row)) * 2048 + k0t * 64 + c8];
  }
#pragma unroll
  for (int it = 0; it < 4; ++it) {
    int slot = it * 128 + tid, row = slot >> 3, c8 = (slot & 7) * 8;
    *(bf16x8*)&Ks[row * 72 + c8] = kreg[it];
    *(bf16x8*)&Vs[row * 72 + c8] = vreg[it];
  }
  __syncthreads();

  for (int kt = k0t; kt < kend; ++kt) {
    if (kt + 1 < kend) {
#pragma unroll
      for (int it = 0; it < 4; ++it) {
        int slot = it * 128 + tid, row = slot >> 3, c8 = (slot & 7) * 8;
        kreg[it] = *(const bf16x8*)&kvg[(size_t)(b * 2048 + (kt + 1) * 64 + row) * 2048 + h * 64 + c8];
        vreg[it] = *(const bf16x8*)&vtg[((size_t)(bh * 64 + row)) * 2048 + (kt + 1) * 64 + c8];
      }
    }

    // S^T = K Q^T
    f32x4 s[4];
    __builtin_amdgcn_s_setprio(1);
#pragma unroll
    for (int n = 0; n < 4; ++n) {
      f32x4 z = {};
#pragma unroll
      for (int ks = 0; ks < 2; ++ks) {
        bf16x8 kf = *(const bf16x8*)&Ks[(n * 16 + lr) * 72 + ks * 32 + lg * 8];
        z = __builtin_amdgcn_mfma_f32_16x16x32_bf16(kf, qf[ks], z, 0, 0, 0);
      }
      s[n] = z;
    }
    __builtin_amdgcn_s_setprio(0);

    const int tok = tileokg[b * 32 + kt];
    const bool diag = (kt == nkv - 1);
    float p[4][4];
    float mx = -1e30f;
    if (tok) {
      if (diag) {
#pragma unroll
        for (int n = 0; n < 4; ++n)
#pragma unroll
          for (int i = 0; i < 4; ++i) {
            float v = (n * 16 + lg * 4 + i <= diagoff) ? s[n][i] : -1e30f;
            p[n][i] = v;
            mx = fmaxf(mx, v);
          }
      } else {
#pragma unroll
        for (int n = 0; n < 4; ++n)
#pragma unroll
          for (int i = 0; i < 4; ++i) {
            p[n][i] = s[n][i];
            mx = fmaxf(mx, s[n][i]);
          }
      }
    } else {
#pragma unroll
      for (int n = 0; n < 4; ++n)
#pragma unroll
        for (int i = 0; i < 4; ++i) {
          int keyl = n * 16 + lg * 4 + i;
          float v = s[n][i] + biasg[b * 2048 + kt * 64 + keyl];
          if (diag) v = (keyl <= diagoff) ? v : -1e30f;
          p[n][i] = v;
          mx = fmaxf(mx, v);
        }
    }
    mx = fmaxf(mx, __shfl_xor(mx, 16, 64));
    mx = fmaxf(mx, __shfl_xor(mx, 32, 64));

    // T13 defer-rescale
    if (__any(mx - m_i > 8.0f)) {
      float mn = fmaxf(m_i, mx);
      float sc = fexp2(m_i - mn);
      m_i = mn;
      l_part *= sc;
      float scb[4];
#pragma unroll
      for (int i = 0; i < 4; ++i) scb[i] = __shfl(sc, lg * 4 + i, 64);
#pragma unroll
      for (int dt = 0; dt < 4; ++dt)
#pragma unroll
        for (int i = 0; i < 4; ++i) acc[dt][i] *= scb[i];
    }

    float rs = 0.f;
#pragma unroll
    for (int n = 0; n < 4; ++n)
#pragma unroll
      for (int i = 0; i < 4; ++i) {
        float e = fexp2(p[n][i] - m_i);
        p[n][i] = e;
        rs += e;
      }
    l_part += rs;

    // P -> PV A-fragments in registers (V pre-permuted)
    unsigned pk[4][2];
#pragma unroll
    for (int n = 0; n < 4; ++n) {
      asm("v_cvt_pk_bf16_f32 %0, %1, %2" : "=v"(pk[n][0]) : "v"(p[n][0]), "v"(p[n][1]));
      asm("v_cvt_pk_bf16_f32 %0, %1, %2" : "=v"(pk[n][1]) : "v"(p[n][2]), "v"(p[n][3]));
    }
    bf16x8 paf[2];
#pragma unroll
    for (int ks = 0; ks < 2; ++ks) {
      u32x4 uv;
      uv[0] = pk[2 * ks][0];
      uv[1] = pk[2 * ks][1];
      uv[2] = pk[2 * ks + 1][0];
      uv[3] = pk[2 * ks + 1][1];
      paf[ks] = __builtin_bit_cast(bf16x8, uv);
    }

    __builtin_amdgcn_s_setprio(1);
#pragma unroll
    for (int ks = 0; ks < 2; ++ks)
#pragma unroll
      for (int dt = 0; dt < 4; ++dt) {
        bf16x8 vf = *(const bf16x8*)&Vs[(dt * 16 + lr) * 72 + ks * 32 + lg * 8];
        acc[dt] = __builtin_amdgcn_mfma_f32_16x16x32_bf16(paf[ks], vf, acc[dt], 0, 0, 0);
      }
    __builtin_amdgcn_s_setprio(0);

    __syncthreads();
    if (kt + 1 < kend) {
#pragma unroll
      for (int it = 0; it < 4; ++it) {
        int slot = it * 128 + tid, row = slot >> 3, c8 = (slot & 7) * 8;
        *(bf16x8*)&Ks[row * 72 + c8] = kreg[it];
        *(bf16x8*)&Vs[row * 72 + c8] = vreg[it];
      }
      __syncthreads();
    }
  }

  // epilogue: write unnormalized partial
  float lt = l_part;
  lt += __shfl_xor(lt, 16, 64);
  lt += __shfl_xor(lt, 32, 64);
  float* pb = partg + (size_t)(bh * 160 + y2) * PSTRIDE;
#pragma unroll
  for (int dt = 0; dt < 4; ++dt)
#pragma unroll
    for (int i = 0; i < 4; ++i)
      pb[(w * 16 + lg * 4 + i) * 64 + dt * 16 + lr] = acc[dt][i];
  if (lg == 0) {
    pb[2048 + w * 16 + lr] = m_i;
    pb[2048 + 32 + w * 16 + lr] = lt;
  }
}

// ---------- combine partials: out = sum_c w_c O_c / sum_c w_c l_c ----------
__global__ __launch_bounds__(256) void attn_reduce(const float* __restrict__ partg,
                                                   float* __restrict__ outg) {
  const int bh = blockIdx.x, qt32 = blockIdx.y;
  const int b = bh >> 4, h = bh & 15;
  const int d = threadIdx.x & 63, rg = threadIdx.x >> 6;  // 4 row-groups
  const int band = qt32 >> 4;
  const int nch = band + 1;
  int y2base;
  if (band == 0)      y2base = qt32;
  else if (band == 1) y2base = 16 + (qt32 - 16) * 2;
  else if (band == 2) y2base = 48 + (qt32 - 32) * 3;
  else                y2base = 96 + (qt32 - 48) * 4;
  const float* p0 = partg + (size_t)(bh * 160 + y2base) * PSTRIDE;

  for (int r = rg; r < 32; r += 4) {
    float m = -1e30f;
    for (int c = 0; c < nch; ++c) m = fmaxf(m, p0[c * PSTRIDE + 2048 + r]);
    float osum = 0.f, lsum = 0.f;
    for (int c = 0; c < nch; ++c) {
      float wgt = fexp2(p0[c * PSTRIDE + 2048 + r] - m);
      lsum += wgt * p0[c * PSTRIDE + 2048 + 32 + r];
      osum += wgt * p0[c * PSTRIDE + r * 64 + d];
    }
    outg[(size_t)(b * 2048 + qt32 * 32 + r) * 1024 + h * 64 + d] = osum / lsum;
  }
}

// ---------- launch ----------
extern "C" void kernel_launch(void* const* d_in, const int* in_sizes, int n_in,
                              void* d_out, int out_size, void* d_ws, size_t ws_size,
                              hipStream_t stream) {
  const float* x    = (const float*)d_in[0];
  const int*   mask = (const int*)d_in[1];
  const float* w_q  = (const float*)d_in[2];
  const float* w_d  = (const float*)d_in[3];
  const float* w_k  = (const float*)d_in[4];
  const float* w_v  = (const float*)d_in[5];
  float* out = (float*)d_out;

  char* ws = (char*)d_ws;
  size_t off = 0;
  auto alloc = [&](size_t elems) {
    unsigned short* p = (unsigned short*)(ws + off);
    off += ((elems * 2 + 255) & ~(size_t)255);
    return p;
  };
  unsigned short* x_bf = alloc(4194304);      // [4096][1024]
  unsigned short* wqdt = alloc(1152 * 1024);  // [1152][1024]
  unsigned short* wkvt = alloc(2048 * 128);   // [2048][128]
  unsigned short* qlat = alloc(4096 * 1152);  // [4096][1152]: q | latent
  unsigned short* kv   = alloc(4096 * 2048);  // [4096][2048]: K in cols 0..1023
  unsigned short* vt   = alloc(4194304);      // [32][64][2048], pv_perm'd
  float* bias = (float*)alloc(8192);          // 4096 floats
  int* tileok = (int*)alloc(128);             // 64 ints
  float* part = (float*)alloc((size_t)32 * 160 * PSTRIDE * 2);  // 43.25 MB fp32 partials

  prep_kernel<<<2448, 256, 0, stream>>>(x, mask, w_q, w_d, w_k, w_v, x_bf, wqdt, wkvt, bias, tileok);

  gemm_bt<64><<<dim3(32, 18), 256, 0, stream>>>(x_bf, 1024, wqdt, 1024, qlat, 1152, 1024);
  gemm_kv<<<dim3(32, 16), 256, 0, stream>>>(qlat + 1024, wkvt, kv, vt);

  attn_kernel<<<dim3(32, 160), 128, 0, stream>>>(qlat, kv, vt, bias, tileok, part);
  attn_reduce<<<dim3(32, 64), 256, 0, stream>>>(part, out);
}

// Round 12
// 87.019 us; speedup vs baseline: 1.2874x; 1.1860x over previous
//
#include <hip/hip_runtime.h>

// ---------- types & helpers ----------
typedef __attribute__((ext_vector_type(8))) short bf16x8;
typedef __attribute__((ext_vector_type(4))) float f32x4;
typedef __attribute__((ext_vector_type(4))) unsigned u32x4;

__device__ inline unsigned short f2bf(float f) {
  unsigned u = __builtin_bit_cast(unsigned, f);
  unsigned r = u + 0x7FFFu + ((u >> 16) & 1u);
  return (unsigned short)(r >> 16);
}
__device__ inline float bf2f(unsigned short s) {
  unsigned u = ((unsigned)s) << 16;
  return __builtin_bit_cast(float, u);
}
__device__ inline float fexp2(float x) { return __builtin_amdgcn_exp2f(x); }

__device__ inline void gload_lds16(const unsigned short* g, unsigned short* l) {
  __builtin_amdgcn_global_load_lds(
      (const __attribute__((address_space(1))) unsigned int*)g,
      (__attribute__((address_space(3))) unsigned int*)l, 16, 0, 0);
}

// PV key-permutation: key kappa (within 64-tile) -> slot k'
__device__ __host__ inline int pv_perm(int k) {
  return ((k >> 5) & 1) * 32 + ((k >> 2) & 3) * 8 + ((k >> 4) & 1) * 4 + (k & 3);
}

// ---------- fused preprocessing: x->bf16, 4 weight transposes, mask bias + tileok ----------
__global__ __launch_bounds__(256) void prep_kernel(
    const float* __restrict__ x, const int* __restrict__ mask,
    const float* __restrict__ w_q, const float* __restrict__ w_d,
    const float* __restrict__ w_k, const float* __restrict__ w_v,
    unsigned short* __restrict__ x_bf, unsigned short* __restrict__ wqdt,
    unsigned short* __restrict__ wkvt, float* __restrict__ bias,
    int* __restrict__ tileok) {
  int bid = blockIdx.x;
  if (bid < 1024) {  // x fp32 -> bf16
    int base = bid * 4096 + threadIdx.x * 4;
#pragma unroll
    for (int it = 0; it < 4; ++it) {
      int idx = base + it * 1024;
      float4 v = *(const float4*)&x[idx];
      ushort4 o;
      o.x = f2bf(v.x); o.y = f2bf(v.y); o.z = f2bf(v.z); o.w = f2bf(v.w);
      *(ushort4*)&x_bf[idx] = o;
    }
    return;
  }
  int tb = bid - 1024;
  if (tb >= 1408) {  // mask -> additive bias + per-64-key-tile all-valid flag
    int i = (tb - 1408) * 256 + threadIdx.x;
    int mv = mask[i];
    bias[i] = mv ? 0.0f : -1e30f;
    int ok = __all(mv != 0);
    if ((threadIdx.x & 63) == 0) tileok[i >> 6] = ok;
    return;
  }
  const float* in; unsigned short* out; int R, C, tr, tc;
  if (tb < 1024)      { in = w_q; out = wqdt;               R = 1024; C = 1024; tr = tb >> 5; tc = tb & 31; }
  else if (tb < 1152) { int t2 = tb - 1024; in = w_d; out = wqdt + 1024 * 1024; R = 1024; C = 128; tr = t2 >> 2; tc = t2 & 3; }
  else if (tb < 1280) { int t2 = tb - 1152; in = w_k; out = wkvt;               R = 128; C = 1024; tr = t2 >> 5; tc = t2 & 31; }
  else                { int t2 = tb - 1280; in = w_v; out = wkvt + 1024 * 128;  R = 128; C = 1024; tr = t2 >> 5; tc = t2 & 31; }
  __shared__ float t[32][33];
  int r0 = tr * 32, c0 = tc * 32;
  int tx = threadIdx.x & 31, ty = threadIdx.x >> 5;
  for (int r = ty; r < 32; r += 8)
    t[r][tx] = in[(size_t)(r0 + r) * C + c0 + tx];
  __syncthreads();
  for (int cc = ty; cc < 32; cc += 8)
    out[(size_t)(c0 + cc) * R + r0 + tx] = f2bf(t[tx][cc]);
}

// ---------- GEMM: C[M][N] = A[M][K] * Bt[N][K]^T ----------
template <int BN>
__global__ __launch_bounds__(256) void gemm_bt(const unsigned short* __restrict__ A, int lda,
                                               const unsigned short* __restrict__ Bt, int ldb,
                                               unsigned short* __restrict__ C, int ldc,
                                               int K) {
  constexpr int WM = (BN == 128) ? 2 : 4;
  constexpr int WN = 4 / WM;
  constexpr int MR = 128 / WM / 16;
  constexpr int NR = BN / WN / 16;
  constexpr int RPW = 128 / WM;
  constexpr int CPW = BN / WN;
  __shared__ unsigned short As[128 * 32];
  __shared__ unsigned short Bs[BN * 32];
  int m0 = blockIdx.x * 128, n0 = blockIdx.y * BN;
  int tid = threadIdx.x, w = tid >> 6, l = tid & 63;
  int lr = l & 15, lg = l >> 4;
  int wr = w / WN, wc = w % WN;
  f32x4 acc[MR][NR] = {};

  for (int k0 = 0; k0 < K; k0 += 32) {
    __syncthreads();
#pragma unroll
    for (int it = 0; it < 2; ++it) {
      int c = w * 2 + it;
      int row = c * 16 + (l >> 2);
      int col = (l & 3) * 8;
      gload_lds16(&A[(size_t)(m0 + row) * lda + k0 + col], &As[c * 512 + l * 8]);
    }
    if constexpr (BN == 128) {
#pragma unroll
      for (int it = 0; it < 2; ++it) {
        int c = w * 2 + it;
        int row = c * 16 + (l >> 2);
        int col = (l & 3) * 8;
        gload_lds16(&Bt[(size_t)(n0 + row) * ldb + k0 + col], &Bs[c * 512 + l * 8]);
      }
    } else {
      int row = w * 16 + (l >> 2);
      int col = (l & 3) * 8;
      gload_lds16(&Bt[(size_t)(n0 + row) * ldb + k0 + col], &Bs[w * 512 + l * 8]);
    }
    __syncthreads();
    bf16x8 af[MR], bfr[NR];
#pragma unroll
    for (int m = 0; m < MR; ++m)
      af[m] = *(const bf16x8*)&As[(wr * RPW + m * 16 + lr) * 32 + lg * 8];
#pragma unroll
    for (int n = 0; n < NR; ++n)
      bfr[n] = *(const bf16x8*)&Bs[(wc * CPW + n * 16 + lr) * 32 + lg * 8];
    __builtin_amdgcn_s_setprio(1);
#pragma unroll
    for (int m = 0; m < MR; ++m)
#pragma unroll
      for (int n = 0; n < NR; ++n)
        acc[m][n] = __builtin_amdgcn_mfma_f32_16x16x32_bf16(af[m], bfr[n], acc[m][n], 0, 0, 0);
    __builtin_amdgcn_s_setprio(0);
  }

#pragma unroll
  for (int m = 0; m < MR; ++m)
#pragma unroll
    for (int n = 0; n < NR; ++n)
#pragma unroll
      for (int i = 0; i < 4; ++i)
        C[(size_t)(m0 + wr * RPW + m * 16 + lg * 4 + i) * ldc + n0 + wc * CPW + n * 16 + lr] =
            f2bf(acc[m][n][i]);
}

// ---------- gemm2 with fused V transpose+permute epilogue ----------
__global__ __launch_bounds__(256) void gemm_kv(const unsigned short* __restrict__ A,
                                               const unsigned short* __restrict__ Bt,
                                               unsigned short* __restrict__ kvK,
                                               unsigned short* __restrict__ vt) {
  __shared__ unsigned short As[128 * 32];
  __shared__ unsigned short Bs[128 * 32];
  int m0 = blockIdx.x * 128, n0 = blockIdx.y * 128;
  int tid = threadIdx.x, w = tid >> 6, l = tid & 63;
  int lr = l & 15, lg = l >> 4;
  int wr = w >> 1, wc = w & 1;
  f32x4 acc[4][4] = {};

  for (int k0 = 0; k0 < 128; k0 += 32) {
    __syncthreads();
#pragma unroll
    for (int it = 0; it < 2; ++it) {
      int c = w * 2 + it;
      int row = c * 16 + (l >> 2);
      int col = (l & 3) * 8;
      gload_lds16(&A[(size_t)(m0 + row) * 1152 + k0 + col], &As[c * 512 + l * 8]);
      gload_lds16(&Bt[(size_t)(n0 + row) * 128 + k0 + col], &Bs[c * 512 + l * 8]);
    }
    __syncthreads();
    bf16x8 af[4], bfr[4];
#pragma unroll
    for (int m = 0; m < 4; ++m)
      af[m] = *(const bf16x8*)&As[(wr * 64 + m * 16 + lr) * 32 + lg * 8];
#pragma unroll
    for (int n = 0; n < 4; ++n)
      bfr[n] = *(const bf16x8*)&Bs[(wc * 64 + n * 16 + lr) * 32 + lg * 8];
    __builtin_amdgcn_s_setprio(1);
#pragma unroll
    for (int m = 0; m < 4; ++m)
#pragma unroll
      for (int n = 0; n < 4; ++n)
        acc[m][n] = __builtin_amdgcn_mfma_f32_16x16x32_bf16(af[m], bfr[n], acc[m][n], 0, 0, 0);
    __builtin_amdgcn_s_setprio(0);
  }

  if (blockIdx.y < 8) {  // K half
#pragma unroll
    for (int m = 0; m < 4; ++m)
#pragma unroll
      for (int n = 0; n < 4; ++n)
#pragma unroll
        for (int i = 0; i < 4; ++i)
          kvK[(size_t)(m0 + wr * 64 + m * 16 + lg * 4 + i) * 2048 + n0 + wc * 64 + n * 16 + lr] =
              f2bf(acc[m][n][i]);
  } else {  // V half: transposed + pv_perm'd
#pragma unroll
    for (int m = 0; m < 4; ++m)
#pragma unroll
      for (int n = 0; n < 4; ++n) {
        int vc = n0 - 1024 + wc * 64 + n * 16 + lr;
        int hh = vc >> 6, dd = vc & 63;
        int row0 = m0 + wr * 64 + m * 16 + lg * 4;
        int bb = row0 >> 11, t0 = row0 & 2047;
        size_t vrow = (size_t)((bb * 16 + hh) * 64 + dd);
        int slot = (t0 >> 6) * 64 + pv_perm(t0 & 63);
        ushort4 o;
        o.x = f2bf(acc[m][n][0]); o.y = f2bf(acc[m][n][1]);
        o.z = f2bf(acc[m][n][2]); o.w = f2bf(acc[m][n][3]);
        *(ushort4*)&vt[vrow * 2048 + slot] = o;
      }
  }
}

// ---------- flash attention: QBLK=64, 2 waves x 32 q-rows, LDS-staged KV ----------
// grid (bh=32, y=32), qt = 31 - y (heaviest first). Wave w owns rows
// qt*64 + w*32 + qb*16 + lr (qb=0,1). 64-key tiles; nkv = qt + 1.
__global__ __launch_bounds__(128, 2) void attn_kernel(const unsigned short* __restrict__ qg,
                                                      const unsigned short* __restrict__ kvg,
                                                      const unsigned short* __restrict__ vtg,
                                                      const float* __restrict__ biasg,
                                                      const int* __restrict__ tileokg,
                                                      float* __restrict__ outg) {
  const int bh = blockIdx.x, qt = 31 - blockIdx.y;
  const int b = bh >> 4, h = bh & 15;
  const int tid = threadIdx.x, w = tid >> 6, l = tid & 63;
  const int lr = l & 15, lg = l >> 4;

  __shared__ unsigned short Ks[64 * 72];  // [key][d]
  __shared__ unsigned short Vs[64 * 72];  // [d][permuted key]

  const int qrow0 = qt * 64 + w * 32;     // wave base row
  const int nkv = qt + 1;
  const int dov0 = w * 32 + lr;           // causal limit qb=0; +16 for qb=1
  const float QSCALE = 0.125f * 1.44269504089f;

  // Q fragments, two 16-row column blocks per wave
  bf16x8 qf[2][2];
#pragma unroll
  for (int qb = 0; qb < 2; ++qb)
#pragma unroll
    for (int ks = 0; ks < 2; ++ks) {
      bf16x8 raw = *(const bf16x8*)&qg[(size_t)(b * 2048 + qrow0 + qb * 16 + lr) * 1152 +
                                       h * 64 + ks * 32 + lg * 8];
#pragma unroll
      for (int j = 0; j < 8; ++j)
        raw[j] = (short)f2bf(bf2f((unsigned short)raw[j]) * QSCALE);
      qf[qb][ks] = raw;
    }

  f32x4 acc[4][2] = {};            // [dt][qb]
  float m_i[2] = {-1e30f, -1e30f};
  float l_part[2] = {0.f, 0.f};

  // prologue: stage tile 0 (128 threads -> 4 chunks per tensor)
  bf16x8 kreg[4], vreg[4];
#pragma unroll
  for (int it = 0; it < 4; ++it) {
    int slot = it * 128 + tid, row = slot >> 3, c8 = (slot & 7) * 8;
    kreg[it] = *(const bf16x8*)&kvg[(size_t)(b * 2048 + row) * 2048 + h * 64 + c8];
    vreg[it] = *(const bf16x8*)&vtg[((size_t)(bh * 64 + row)) * 2048 + c8];
  }
#pragma unroll
  for (int it = 0; it < 4; ++it) {
    int slot = it * 128 + tid, row = slot >> 3, c8 = (slot & 7) * 8;
    *(bf16x8*)&Ks[row * 72 + c8] = kreg[it];
    *(bf16x8*)&Vs[row * 72 + c8] = vreg[it];
  }
  __syncthreads();

  for (int kt = 0; kt < nkv; ++kt) {
    // T14 async-stage: issue next tile's global loads now, ds_write after post-PV barrier
    if (kt + 1 < nkv) {
#pragma unroll
      for (int it = 0; it < 4; ++it) {
        int slot = it * 128 + tid, row = slot >> 3, c8 = (slot & 7) * 8;
        kreg[it] = *(const bf16x8*)&kvg[(size_t)(b * 2048 + (kt + 1) * 64 + row) * 2048 + h * 64 + c8];
        vreg[it] = *(const bf16x8*)&vtg[((size_t)(bh * 64 + row)) * 2048 + (kt + 1) * 64 + c8];
      }
    }

    // S^T = K Q^T: K-frag loaded once per (n,ks), reused for both qb
    f32x4 s[2][4];
    __builtin_amdgcn_s_setprio(1);
#pragma unroll
    for (int n = 0; n < 4; ++n) {
      bf16x8 kf0 = *(const bf16x8*)&Ks[(n * 16 + lr) * 72 + lg * 8];
      bf16x8 kf1 = *(const bf16x8*)&Ks[(n * 16 + lr) * 72 + 32 + lg * 8];
#pragma unroll
      for (int qb = 0; qb < 2; ++qb) {
        f32x4 z = {};
        z = __builtin_amdgcn_mfma_f32_16x16x32_bf16(kf0, qf[qb][0], z, 0, 0, 0);
        z = __builtin_amdgcn_mfma_f32_16x16x32_bf16(kf1, qf[qb][1], z, 0, 0, 0);
        s[qb][n] = z;
      }
    }
    __builtin_amdgcn_s_setprio(0);

    const int tok = tileokg[b * 32 + kt];
    const bool diag = (kt == nkv - 1);
    float mx[2] = {-1e30f, -1e30f};
    if (tok) {
      if (diag) {
#pragma unroll
        for (int qb = 0; qb < 2; ++qb)
#pragma unroll
          for (int n = 0; n < 4; ++n)
#pragma unroll
            for (int i = 0; i < 4; ++i) {
              int keyl = n * 16 + lg * 4 + i;
              float v = (keyl <= dov0 + qb * 16) ? s[qb][n][i] : -1e30f;
              s[qb][n][i] = v;
              mx[qb] = fmaxf(mx[qb], v);
            }
      } else {
#pragma unroll
        for (int qb = 0; qb < 2; ++qb)
#pragma unroll
          for (int n = 0; n < 4; ++n)
#pragma unroll
            for (int i = 0; i < 4; ++i)
              mx[qb] = fmaxf(mx[qb], s[qb][n][i]);
      }
    } else {  // rare general-mask path
#pragma unroll
      for (int n = 0; n < 4; ++n)
#pragma unroll
        for (int i = 0; i < 4; ++i) {
          int keyl = n * 16 + lg * 4 + i;
          float bsv = biasg[b * 2048 + kt * 64 + keyl];
#pragma unroll
          for (int qb = 0; qb < 2; ++qb) {
            float v = s[qb][n][i] + bsv;
            if (diag) v = (keyl <= dov0 + qb * 16) ? v : -1e30f;
            s[qb][n][i] = v;
            mx[qb] = fmaxf(mx[qb], v);
          }
        }
    }
#pragma unroll
    for (int qb = 0; qb < 2; ++qb) {
      mx[qb] = fmaxf(mx[qb], __shfl_xor(mx[qb], 16, 64));
      mx[qb] = fmaxf(mx[qb], __shfl_xor(mx[qb], 32, 64));
    }

    // T13 defer-rescale (THR=8 in log2 domain)
    float g = fmaxf(mx[0] - m_i[0], mx[1] - m_i[1]);
    if (__any(g > 8.0f)) {
#pragma unroll
      for (int qb = 0; qb < 2; ++qb) {
        float mn = fmaxf(m_i[qb], mx[qb]);
        float sc = fexp2(m_i[qb] - mn);
        m_i[qb] = mn;
        l_part[qb] *= sc;
        float scb[4];
#pragma unroll
        for (int i = 0; i < 4; ++i) scb[i] = __shfl(sc, lg * 4 + i, 64);
#pragma unroll
        for (int dt = 0; dt < 4; ++dt)
#pragma unroll
          for (int i = 0; i < 4; ++i) acc[dt][qb][i] *= scb[i];
      }
    }

#pragma unroll
    for (int qb = 0; qb < 2; ++qb) {
      float rs = 0.f;
#pragma unroll
      for (int n = 0; n < 4; ++n)
#pragma unroll
        for (int i = 0; i < 4; ++i) {
          float e = fexp2(s[qb][n][i] - m_i[qb]);
          s[qb][n][i] = e;
          rs += e;
        }
      l_part[qb] += rs;
    }

    // P -> PV A-fragments in registers (V pre-permuted by pv_perm)
    bf16x8 paf[2][2];
#pragma unroll
    for (int qb = 0; qb < 2; ++qb)
#pragma unroll
      for (int ks = 0; ks < 2; ++ks) {
        unsigned t0, t1, t2, t3;
        asm("v_cvt_pk_bf16_f32 %0, %1, %2" : "=v"(t0) : "v"(s[qb][2 * ks][0]), "v"(s[qb][2 * ks][1]));
        asm("v_cvt_pk_bf16_f32 %0, %1, %2" : "=v"(t1) : "v"(s[qb][2 * ks][2]), "v"(s[qb][2 * ks][3]));
        asm("v_cvt_pk_bf16_f32 %0, %1, %2" : "=v"(t2) : "v"(s[qb][2 * ks + 1][0]), "v"(s[qb][2 * ks + 1][1]));
        asm("v_cvt_pk_bf16_f32 %0, %1, %2" : "=v"(t3) : "v"(s[qb][2 * ks + 1][2]), "v"(s[qb][2 * ks + 1][3]));
        u32x4 uv;
        uv[0] = t0; uv[1] = t1; uv[2] = t2; uv[3] = t3;
        paf[qb][ks] = __builtin_bit_cast(bf16x8, uv);
      }

    // O += P V: V-frag loaded once per (dt,ks), reused for both qb
    __builtin_amdgcn_s_setprio(1);
#pragma unroll
    for (int ks = 0; ks < 2; ++ks)
#pragma unroll
      for (int dt = 0; dt < 4; ++dt) {
        bf16x8 vf = *(const bf16x8*)&Vs[(dt * 16 + lr) * 72 + ks * 32 + lg * 8];
#pragma unroll
        for (int qb = 0; qb < 2; ++qb)
          acc[dt][qb] = __builtin_amdgcn_mfma_f32_16x16x32_bf16(paf[qb][ks], vf, acc[dt][qb], 0, 0, 0);
      }
    __builtin_amdgcn_s_setprio(0);

    __syncthreads();
    if (kt + 1 < nkv) {
#pragma unroll
      for (int it = 0; it < 4; ++it) {
        int slot = it * 128 + tid, row = slot >> 3, c8 = (slot & 7) * 8;
        *(bf16x8*)&Ks[row * 72 + c8] = kreg[it];
        *(bf16x8*)&Vs[row * 72 + c8] = vreg[it];
      }
      __syncthreads();
    }
  }

  // epilogue: finish l reduction, normalize, store
#pragma unroll
  for (int qb = 0; qb < 2; ++qb) {
    float lt = l_part[qb];
    lt += __shfl_xor(lt, 16, 64);
    lt += __shfl_xor(lt, 32, 64);
    float inv = 1.f / lt;
    float invb[4];
#pragma unroll
    for (int i = 0; i < 4; ++i) invb[i] = __shfl(inv, lg * 4 + i, 64);
#pragma unroll
    for (int dt = 0; dt < 4; ++dt)
#pragma unroll
      for (int i = 0; i < 4; ++i)
        outg[(size_t)(b * 2048 + qrow0 + qb * 16 + lg * 4 + i) * 1024 + h * 64 + dt * 16 + lr] =
            acc[dt][qb][i] * invb[i];
  }
}

// ---------- launch ----------
extern "C" void kernel_launch(void* const* d_in, const int* in_sizes, int n_in,
                              void* d_out, int out_size, void* d_ws, size_t ws_size,
                              hipStream_t stream) {
  const float* x    = (const float*)d_in[0];
  const int*   mask = (const int*)d_in[1];
  const float* w_q  = (const float*)d_in[2];
  const float* w_d  = (const float*)d_in[3];
  const float* w_k  = (const float*)d_in[4];
  const float* w_v  = (const float*)d_in[5];
  float* out = (float*)d_out;

  char* ws = (char*)d_ws;
  size_t off = 0;
  auto alloc = [&](size_t elems) {
    unsigned short* p = (unsigned short*)(ws + off);
    off += ((elems * 2 + 255) & ~(size_t)255);
    return p;
  };
  unsigned short* x_bf = alloc(4194304);      // [4096][1024]
  unsigned short* wqdt = alloc(1152 * 1024);  // [1152][1024]
  unsigned short* wkvt = alloc(2048 * 128);   // [2048][128]
  unsigned short* qlat = alloc(4096 * 1152);  // [4096][1152]: q | latent
  unsigned short* kv   = alloc(4096 * 2048);  // [4096][2048]: K in cols 0..1023
  unsigned short* vt   = alloc(4194304);      // [32][64][2048], pv_perm'd
  float* bias = (float*)alloc(8192);          // 4096 floats
  int* tileok = (int*)alloc(128);             // 64 ints

  prep_kernel<<<2448, 256, 0, stream>>>(x, mask, w_q, w_d, w_k, w_v, x_bf, wqdt, wkvt, bias, tileok);

  gemm_bt<64><<<dim3(32, 18), 256, 0, stream>>>(x_bf, 1024, wqdt, 1024, qlat, 1152, 1024);
  gemm_kv<<<dim3(32, 16), 256, 0, stream>>>(qlat + 1024, wkvt, kv, vt);

  attn_kernel<<<dim3(32, 32), 128, 0, stream>>>(qlat, kv, vt, bias, tileok, out);
}